// Round 5
// baseline (321.678 us; speedup 1.0000x reference)
//
#include <hip/hip_runtime.h>

// VQ-VAE vector quantization forward — bit-exact emulation of the numpy ref.
// x: [32,64,64,64] f32 -> flat [N=131072, D=64]; embeddings: [D=64, K=512].
//
// np numerics matched exactly (validated rounds 2-4, absmax 0.0):
//   A   = np.sum(f*f, axis=1)   -> pairwise scalar 8-accumulator path (n=64)
//   B_k = np.sum(e*e, axis=0)   -> sequential over d, separate mul+add
//   sim = flat @ emb            -> sequential FMA chain over d per code
//   dist_k = fl( fl(A + B_k) - fl(2*sim_k) ), argmin = first min
// out = fl(x + fl(q - x)); loss = 1.25 * mean((q-x)^2)
//
// Round 5 — fixes driven by round-4 counters (WRITE_SIZE 106MB vs 32MB out,
// VALU-issue 2.26x essential, occupancy 21.7%):
//  - f[64] parked in AGPRs via explicit v_accvgpr_write/read asm. Rounds 2-4:
//    allocator spilled f to scratch and re-loaded per chunk (the 75MB phantom
//    write traffic). AGPR reads are 1 VALU op, no memory, no latency.
//  - 4-way k-split ACROSS WAVES with kq = readfirstlane(tid>>6): readfirstlane
//    returns an SGPR, so emb addresses are provably uniform -> s_load_dwordx16
//    broadcast (round 3 failed exactly because tid>>6 stayed a VGPR -> vector
//    gathers, VALUBusy 29%). Block = 64 rows x 4 k-quarter waves -> 8192 waves
//    (4 waves/SIMD resident) vs round-4's 2048.
//  - Cross-wave exact first-min combine in LDS + coalesced cooperative
//    epilogue: round-3 code, validated bit-exact.

constexpr int D = 64;
constexpr int K = 512;
constexpr int NROWS = 131072;           // 32*64*64*64 / 64
constexpr long long NELEM = 8388608LL;  // NROWS * D
constexpr int ROWS_PER_BLOCK = 64;
constexpr int KQ = 128;                 // codes per k-quarter (one wave each)

// B_k = ||e_k||^2, sequential non-FMA over d (numpy axis-0 reduction order).
__global__ __launch_bounds__(512) void vq_prep(const float* __restrict__ emb,
                                               float* __restrict__ e2,
                                               float* __restrict__ loss_acc) {
    int k = threadIdx.x;  // 0..511
    float e0 = emb[k];
    float b = __fmul_rn(e0, e0);
    for (int d = 1; d < D; ++d) {
        float e = emb[d * K + k];
        b = __fadd_rn(b, __fmul_rn(e, e));
    }
    e2[k] = b;
    if (k == 0) loss_acc[0] = 0.f;
}

__global__ __launch_bounds__(256, 4) void vq_main(const float* __restrict__ x,
                                                  const float* __restrict__ emb,
                                                  const float* __restrict__ e2,
                                                  float* __restrict__ out,
                                                  float* __restrict__ loss_acc) {
    const int tid = threadIdx.x;
    const int r = tid & 63;  // row within block (lane)
    // k-quarter: wave-uniform BY CONSTRUCTION; readfirstlane makes it an SGPR
    // so the compiler proves emb/e2 addresses uniform -> scalar loads.
    const int kq = __builtin_amdgcn_readfirstlane(tid >> 6);
    const int row = blockIdx.x * ROWS_PER_BLOCK + r;
    const float* xr = x + (size_t)row * D;

    // Row into registers (16 x float4; 4 waves read same 64 rows -> L1 reuse).
    float f[D];
    const float4* xr4 = reinterpret_cast<const float4*>(xr);
#pragma unroll
    for (int j = 0; j < D / 4; ++j) {
        float4 v = xr4[j];
        f[4 * j + 0] = v.x;
        f[4 * j + 1] = v.y;
        f[4 * j + 2] = v.z;
        f[4 * j + 3] = v.w;
    }

    // A = numpy pairwise sum of f*f (n=64 scalar 8-accumulator path).
    float rr[8];
#pragma unroll
    for (int j = 0; j < 8; ++j) rr[j] = __fmul_rn(f[j], f[j]);
#pragma unroll
    for (int i = 8; i < D; i += 8)
#pragma unroll
        for (int j = 0; j < 8; ++j)
            rr[j] = __fadd_rn(rr[j], __fmul_rn(f[i + j], f[i + j]));
    const float A =
        __fadd_rn(__fadd_rn(__fadd_rn(rr[0], rr[1]), __fadd_rn(rr[2], rr[3])),
                  __fadd_rn(__fadd_rn(rr[4], rr[5]), __fadd_rn(rr[6], rr[7])));

    // Park f in AGPRs: f's VGPR live ranges die here -> arch-VGPR pressure ~50,
    // and the values CANNOT be spilled-to-scratch-per-chunk anymore.
    float fa[D];
#pragma unroll
    for (int i = 0; i < D; ++i)
        asm volatile("v_accvgpr_write_b32 %0, %1" : "=a"(fa[i]) : "v"(f[i]));

    // This wave's 128 codes, chunks of 16. emb/e2 addresses uniform (SGPR kq +
    // loop counters) -> s_load_dwordx16 per d feeds 16 FMAs.
    float best = 3.0e38f;
    int bidx = 0;
    const int kbase = kq * KQ;
#pragma unroll 1
    for (int k0 = kbase; k0 < kbase + KQ; k0 += 16) {
        float acc[16];
#pragma unroll
        for (int kk = 0; kk < 16; ++kk) acc[kk] = 0.f;
#pragma unroll
        for (int d = 0; d < D; ++d) {
            float fd;
            asm volatile("v_accvgpr_read_b32 %0, %1" : "=v"(fd) : "a"(fa[d]));
            const float* er = emb + d * K + k0;  // uniform
#pragma unroll
            for (int kk = 0; kk < 16; ++kk)
                acc[kk] = __fmaf_rn(fd, er[kk], acc[kk]);
        }
#pragma unroll
        for (int kk = 0; kk < 16; ++kk) {
            // dist = fl( fl(A + B) - fl(2*sim) )  -- exact np expression order
            float dist = __fsub_rn(__fadd_rn(A, e2[k0 + kk]),
                                   __fmul_rn(2.0f, acc[kk]));
            if (dist < best) {  // strict <: first-min within this wave's range
                best = dist;
                bidx = k0 + kk;
            }
        }
    }

    // Exact cross-wave combine (quarters scan ascending k; equal dist -> keep
    // lower quarter's index == np first-min).
    __shared__ float sdist[4][ROWS_PER_BLOCK];
    __shared__ int sidx[4][ROWS_PER_BLOCK];
    __shared__ int bx[ROWS_PER_BLOCK];
    sdist[kq][r] = best;
    sidx[kq][r] = bidx;
    __syncthreads();
    if (tid < ROWS_PER_BLOCK) {
        float b0 = sdist[0][tid];
        int i0 = sidx[0][tid];
#pragma unroll
        for (int qq = 1; qq < 4; ++qq) {
            float dq = sdist[qq][tid];
            int iq = sidx[qq][tid];
            if (dq < b0) { b0 = dq; i0 = iq; }
        }
        bx[tid] = i0;
    }
    __syncthreads();

    // Cooperative epilogue: block tile = 64 rows x 64 floats = 1024 float4,
    // lane-contiguous 16B loads/stores (coalesced). Validated in round 3.
    float lsum = 0.f;
#pragma unroll
    for (int j = 0; j < 4; ++j) {
        const int e4 = j * 256 + tid;       // float4 index in tile
        const int rr2 = e4 >> 4;            // row in block (16 float4/row)
        const int d0 = (e4 & 15) * 4;
        const size_t gbase = (size_t)(blockIdx.x * ROWS_PER_BLOCK + rr2) * D + d0;
        const float4 xv = *reinterpret_cast<const float4*>(x + gbase);
        const int bi = bx[rr2];
        const float* eq = emb + bi;
        float4 o;
        float qv, t;
        qv = eq[(d0 + 0) * K]; t = __fsub_rn(qv, xv.x);
        lsum = __fmaf_rn(t, t, lsum); o.x = __fadd_rn(xv.x, t);
        qv = eq[(d0 + 1) * K]; t = __fsub_rn(qv, xv.y);
        lsum = __fmaf_rn(t, t, lsum); o.y = __fadd_rn(xv.y, t);
        qv = eq[(d0 + 2) * K]; t = __fsub_rn(qv, xv.z);
        lsum = __fmaf_rn(t, t, lsum); o.z = __fadd_rn(xv.z, t);
        qv = eq[(d0 + 3) * K]; t = __fsub_rn(qv, xv.w);
        lsum = __fmaf_rn(t, t, lsum); o.w = __fadd_rn(xv.w, t);
        *reinterpret_cast<float4*>(out + gbase) = o;
    }

    // Loss reduce: wave shuffle -> LDS across 4 waves -> one atomic per block.
#pragma unroll
    for (int off = 32; off > 0; off >>= 1) lsum += __shfl_down(lsum, off, 64);
    __shared__ float wsum[4];
    if (r == 0) wsum[kq] = lsum;
    __syncthreads();
    if (tid == 0)
        atomicAdd(loss_acc, wsum[0] + wsum[1] + wsum[2] + wsum[3]);
}

__global__ void vq_finalize(const float* __restrict__ loss_acc,
                            float* __restrict__ out_loss) {
    if (threadIdx.x == 0) {
        float m = loss_acc[0] / (float)NELEM;  // /2^23: exact
        out_loss[0] = 1.25f * m;               // == fl(0.25m + m)
    }
}

extern "C" void kernel_launch(void* const* d_in, const int* in_sizes, int n_in,
                              void* d_out, int out_size, void* d_ws, size_t ws_size,
                              hipStream_t stream) {
    const float* x = (const float*)d_in[0];
    const float* emb = (const float*)d_in[1];
    float* out = (float*)d_out;

    float* ws = (float*)d_ws;
    float* loss_acc = ws;      // 1 float
    float* e2 = ws + 64;       // 512 floats

    vq_prep<<<1, 512, 0, stream>>>(emb, e2, loss_acc);
    vq_main<<<NROWS / ROWS_PER_BLOCK, 256, 0, stream>>>(x, emb, e2, out, loss_acc);
    vq_finalize<<<1, 64, 0, stream>>>(loss_acc, out + NELEM);
}

// Round 6
// 184.697 us; speedup vs baseline: 1.7416x; 1.7416x over previous
//
#include <hip/hip_runtime.h>

// VQ-VAE vector quantization forward — bit-exact emulation of the numpy ref.
// x: [32,64,64,64] f32 -> flat [N=131072, D=64]; embeddings: [D=64, K=512].
//
// np numerics matched exactly (validated rounds 2-5, absmax 0.0):
//   A   = np.sum(f*f, axis=1)   -> pairwise scalar 8-accumulator path (n=64)
//   B_k = np.sum(e*e, axis=0)   -> sequential over d, separate mul+add
//   sim = flat @ emb            -> sequential FMA chain over d per code
//   dist_k = fl( fl(A + B_k) - fl(2*sim_k) ), argmin = first min
// out = fl(x + fl(q - x)); loss = 1.25 * mean((q-x)^2)
//
// Round 6 — structural fix for the register-pressure war (R2-R5 history:
// allocator either spilled f[64] to scratch (75MB phantom writes) or my
// asm-volatile pins serialized the inner loop at 2.1x inst inflation):
//  - f lives in LDS, padded stride 65 (bank = (r+d)%32 -> 2-way, free).
//    Inner loop per d: 1 ds_read_b32 (LDS pipe) + 32 v_fmac. NO inline asm.
//    Arch-VGPR need ~50 -> no spill possible, no pins needed.
//  - Keep validated R5 structure: 64 rows x 4 k-quarter waves, kq =
//    readfirstlane(tid>>6) (SGPR -> emb addrs provably uniform -> s_load),
//    exact cross-wave first-min combine, coalesced cooperative epilogue.
//  - LDS/block ~19KB -> 8 blocks/CU; grid 2048 = 8/CU -> 32 waves/CU
//    (~100% occupancy). chunk=32 codes (acc[32]) halves f re-reads vs 16.

constexpr int D = 64;
constexpr int K = 512;
constexpr int NROWS = 131072;           // 32*64*64*64 / 64
constexpr long long NELEM = 8388608LL;  // NROWS * D
constexpr int RPB = 64;                 // rows per block
constexpr int FPAD = 65;                // LDS row stride (bank-conflict-free)
constexpr int KQ = 128;                 // codes per k-quarter wave

// B_k = ||e_k||^2, sequential non-FMA over d (numpy axis-0 reduction order).
__global__ __launch_bounds__(512) void vq_prep(const float* __restrict__ emb,
                                               float* __restrict__ e2,
                                               float* __restrict__ loss_acc) {
    int k = threadIdx.x;  // 0..511
    float e0 = emb[k];
    float b = __fmul_rn(e0, e0);
    for (int d = 1; d < D; ++d) {
        float e = emb[d * K + k];
        b = __fadd_rn(b, __fmul_rn(e, e));
    }
    e2[k] = b;
    if (k == 0) loss_acc[0] = 0.f;
}

__global__ __launch_bounds__(256, 8) void vq_main(const float* __restrict__ x,
                                                  const float* __restrict__ emb,
                                                  const float* __restrict__ e2,
                                                  float* __restrict__ out,
                                                  float* __restrict__ loss_acc) {
    const int tid = threadIdx.x;
    const int r = tid & 63;  // row-in-block == lane
    // k-quarter: SGPR by construction -> emb/e2 addresses provably uniform.
    const int kq = __builtin_amdgcn_readfirstlane(tid >> 6);

    __shared__ float sf[RPB * FPAD];  // 64 rows x stride-65 = 16.6 KB

    // Cooperative coalesced stage: 64 rows x 16 float4 = 1024 float4.
    {
        const size_t base = (size_t)blockIdx.x * RPB * D;
#pragma unroll
        for (int j = 0; j < 4; ++j) {
            const int e4 = j * 256 + tid;     // float4 index in tile
            const int rr = e4 >> 4;
            const int d0 = (e4 & 15) * 4;
            const float4 v =
                *reinterpret_cast<const float4*>(x + base + (size_t)rr * D + d0);
            float* p = &sf[rr * FPAD + d0];
            p[0] = v.x; p[1] = v.y; p[2] = v.z; p[3] = v.w;
        }
    }
    __syncthreads();

    const float* fr = &sf[r * FPAD];  // this thread's row in LDS

    // A = numpy pairwise sum of f*f (n=64 scalar 8-accumulator path).
    float rr8[8];
#pragma unroll
    for (int j = 0; j < 8; ++j) rr8[j] = __fmul_rn(fr[j], fr[j]);
#pragma unroll
    for (int i = 8; i < D; i += 8)
#pragma unroll
        for (int j = 0; j < 8; ++j)
            rr8[j] = __fadd_rn(rr8[j], __fmul_rn(fr[i + j], fr[i + j]));
    const float A =
        __fadd_rn(__fadd_rn(__fadd_rn(rr8[0], rr8[1]), __fadd_rn(rr8[2], rr8[3])),
                  __fadd_rn(__fadd_rn(rr8[4], rr8[5]), __fadd_rn(rr8[6], rr8[7])));

    // This wave's 128 codes in chunks of 32. Per d: 1 ds_read + 32 v_fmac
    // (emb values arrive via scalar broadcast loads; addresses uniform).
    float best = 3.0e38f;
    int bidx = 0;
    const int kbase = kq * KQ;
#pragma unroll 1
    for (int k0 = kbase; k0 < kbase + KQ; k0 += 32) {
        float acc[32];
#pragma unroll
        for (int kk = 0; kk < 32; ++kk) acc[kk] = 0.f;
#pragma unroll 4
        for (int d = 0; d < D; ++d) {
            const float fd = fr[d];              // ds_read_b32, 2-way/free
            const float* er = emb + d * K + k0;  // uniform
#pragma unroll
            for (int kk = 0; kk < 32; ++kk)
                acc[kk] = __fmaf_rn(fd, er[kk], acc[kk]);
        }
#pragma unroll
        for (int kk = 0; kk < 32; ++kk) {
            // dist = fl( fl(A + B) - fl(2*sim) )  -- exact np expression order
            float dist = __fsub_rn(__fadd_rn(A, e2[k0 + kk]),
                                   __fmul_rn(2.0f, acc[kk]));
            if (dist < best) {  // strict <: first-min within this wave's range
                best = dist;
                bidx = k0 + kk;
            }
        }
    }

    // Exact cross-wave combine (quarters scan ascending k; equal dist keeps
    // lower quarter's index == np first-min). Validated round 5.
    __shared__ float sdist[4][RPB];
    __shared__ int sidx[4][RPB];
    __shared__ int bx[RPB];
    sdist[kq][r] = best;
    sidx[kq][r] = bidx;
    __syncthreads();
    if (tid < RPB) {
        float b0 = sdist[0][tid];
        int i0 = sidx[0][tid];
#pragma unroll
        for (int qq = 1; qq < 4; ++qq) {
            float dq = sdist[qq][tid];
            int iq = sidx[qq][tid];
            if (dq < b0) { b0 = dq; i0 = iq; }
        }
        bx[tid] = i0;
    }
    __syncthreads();

    // Cooperative epilogue: 64 rows x 64 floats = 1024 float4, lane-contiguous
    // 16B loads/stores. Validated bit-exact round 5.
    float lsum = 0.f;
#pragma unroll
    for (int j = 0; j < 4; ++j) {
        const int e4 = j * 256 + tid;
        const int rr2 = e4 >> 4;
        const int d0 = (e4 & 15) * 4;
        const size_t gbase = (size_t)(blockIdx.x * RPB + rr2) * D + d0;
        const float4 xv = *reinterpret_cast<const float4*>(x + gbase);
        const int bi = bx[rr2];
        const float* eq = emb + bi;
        float4 o;
        float qv, t;
        qv = eq[(d0 + 0) * K]; t = __fsub_rn(qv, xv.x);
        lsum = __fmaf_rn(t, t, lsum); o.x = __fadd_rn(xv.x, t);
        qv = eq[(d0 + 1) * K]; t = __fsub_rn(qv, xv.y);
        lsum = __fmaf_rn(t, t, lsum); o.y = __fadd_rn(xv.y, t);
        qv = eq[(d0 + 2) * K]; t = __fsub_rn(qv, xv.z);
        lsum = __fmaf_rn(t, t, lsum); o.z = __fadd_rn(xv.z, t);
        qv = eq[(d0 + 3) * K]; t = __fsub_rn(qv, xv.w);
        lsum = __fmaf_rn(t, t, lsum); o.w = __fadd_rn(xv.w, t);
        *reinterpret_cast<float4*>(out + gbase) = o;
    }

    // Loss reduce: wave shuffle -> LDS across 4 waves -> one atomic per block.
#pragma unroll
    for (int off = 32; off > 0; off >>= 1) lsum += __shfl_down(lsum, off, 64);
    __shared__ float wsum[4];
    if (r == 0) wsum[kq] = lsum;
    __syncthreads();
    if (tid == 0)
        atomicAdd(loss_acc, wsum[0] + wsum[1] + wsum[2] + wsum[3]);
}

__global__ void vq_finalize(const float* __restrict__ loss_acc,
                            float* __restrict__ out_loss) {
    if (threadIdx.x == 0) {
        float m = loss_acc[0] / (float)NELEM;  // /2^23: exact
        out_loss[0] = 1.25f * m;               // == fl(0.25m + m)
    }
}

extern "C" void kernel_launch(void* const* d_in, const int* in_sizes, int n_in,
                              void* d_out, int out_size, void* d_ws, size_t ws_size,
                              hipStream_t stream) {
    const float* x = (const float*)d_in[0];
    const float* emb = (const float*)d_in[1];
    float* out = (float*)d_out;

    float* ws = (float*)d_ws;
    float* loss_acc = ws;      // 1 float
    float* e2 = ws + 64;       // 512 floats

    vq_prep<<<1, 512, 0, stream>>>(emb, e2, loss_acc);
    vq_main<<<NROWS / RPB, 256, 0, stream>>>(x, emb, e2, out, loss_acc);
    vq_finalize<<<1, 64, 0, stream>>>(loss_acc, out + NELEM);
}